// Round 6
// baseline (457.049 us; speedup 1.0000x reference)
//
#include <hip/hip_runtime.h>

#define B_TOT   4096
#define T_STEPS 512
#define IN_F    5
#define D_FC    32
#define D_H     64
#define MB      16      // batches per block; DENSE M-tile: batch b = A-row b
#define NROW    16
#define ROWE    72      // f16 elems per row (64 h + 8 pad; 144B rows, 16B-aligned)

typedef _Float16 h8 __attribute__((ext_vector_type(8)));
typedef __fp16   h2 __attribute__((ext_vector_type(2)));
typedef float    f4 __attribute__((ext_vector_type(4)));

__device__ __forceinline__ float fexp2(float x) { return __builtin_amdgcn_exp2f(x); }
__device__ __forceinline__ float frcp(float x)  { return __builtin_amdgcn_rcpf(x); }

__global__ __launch_bounds__(512) void lstm_mfma(
    const float* __restrict__ x,
    const float* __restrict__ W0,
    const float* __restrict__ b0,
    const float* __restrict__ W_ih,
    const float* __restrict__ W_hh,
    const float* __restrict__ b_ih,
    const float* __restrict__ b_hh,
    const float* __restrict__ Wo,
    const float* __restrict__ bo,
    float* __restrict__ out)
{
    // double-buffered h(t-1), f16: H[buf][batch-row][hidden]
    __shared__ __align__(16) _Float16 H[2][NROW][ROWE];
    // partial-acc exchange: [writer-half][pair][lane][2 rows x f4(gates)]
    __shared__ __align__(16) float EX[2][4][64][8];

    const int tid  = threadIdx.x;
    const int lane = tid & 63;
    const int w    = tid >> 6;      // 0..7
    const int p    = w & 3;         // j-tile: owns hidden j in [p*16, p*16+16)
    const int half = w >> 2;        // K-half: 0 -> x + h[0:32], 1 -> h[32:64]
    const int col  = lane & 15;
    const int quad = lane >> 4;
    const int bblk = blockIdx.x * MB;

    const float K1 = 1.4426950408889634f;   // log2(e)
    const float K2 = 2.8853900817779268f;   // 2*log2(e)

    // ---- resident W_hh B-fragment: only THIS wave's K-chunk ----
    h8 Bf[4];
    #pragma unroll
    for (int q = 0; q < 4; ++q) {
        const int row = q * 64 + p * 16 + col;
        h8 f;
        #pragma unroll
        for (int jj = 0; jj < 8; ++jj) {
            const int k = half * 32 + quad * 8 + jj;
            f[jj] = (_Float16)W_hh[row * D_H + k];
        }
        Bf[q] = f;
    }

    // ---- folded x-side weights (half 0 only): Weff = W_ih * W0, K=32-padded ----
    h8 Bx[4];
    #pragma unroll
    for (int q = 0; q < 4; ++q) {
        #pragma unroll
        for (int jj = 0; jj < 8; ++jj) Bx[q][jj] = (_Float16)0.0f;
    }
    if (half == 0 && quad == 0) {
        #pragma unroll
        for (int q = 0; q < 4; ++q) {
            const int row = q * 64 + p * 16 + col;
            #pragma unroll
            for (int jj = 0; jj < IN_F; ++jj) {
                float s = 0.0f;
                #pragma unroll
                for (int m = 0; m < D_FC; ++m)
                    s = fmaf(W_ih[row * D_FC + m], W0[m * IN_F + jj], s);
                Bx[q][jj] = (_Float16)s;
            }
        }
    }

    // ---- folded bias, pre-scaled into the exp2 argument ----
    float sb[4];
    #pragma unroll
    for (int q = 0; q < 4; ++q) {
        const int row = q * 64 + p * 16 + col;
        float s = b_ih[row] + b_hh[row];
        #pragma unroll
        for (int m = 0; m < D_FC; ++m)
            s = fmaf(W_ih[row * D_FC + m], b0[m], s);
        sb[q] = s;
    }
    const float nbi = -K1 * sb[0];
    const float nbf = -K1 * sb[1];
    const float pbg =  K2 * sb[2];
    const float nbo = -K1 * sb[3];

    // ---- zero both LDS H buffers (h(-1)=0) ----
    for (int i = tid; i < 2 * NROW * ROWE; i += 512)
        ((_Float16*)H)[i] = (_Float16)0.0f;

    // ---- x feed (half 0 waves only): A-frag row = batch = col ----
    const float* xb = x + (size_t)(bblk + col) * T_STEPS * IN_F;

    union AxU { h8 v; h2 pk[4]; };
    AxU Ax[2];
    #pragma unroll
    for (int jj = 0; jj < 8; ++jj) { Ax[0].v[jj] = (_Float16)0.0f; Ax[1].v[jj] = (_Float16)0.0f; }
    f4 xv[2]; float x4[2];
    if (half == 0) {
        const f4 v0 = *(const f4*)xb;
        const float s0 = xb[4];
        Ax[0].pk[0] = __builtin_amdgcn_cvt_pkrtz(v0[0], v0[1]);
        Ax[0].pk[1] = __builtin_amdgcn_cvt_pkrtz(v0[2], v0[3]);
        Ax[0].pk[2] = __builtin_amdgcn_cvt_pkrtz(s0, 0.0f);
        xv[0] = *(const f4*)(xb + IN_F);      x4[0] = xb[IN_F + 4];      // x(1)
        xv[1] = *(const f4*)(xb + 2 * IN_F);  x4[1] = xb[2 * IN_F + 4];  // x(2)
    }

    f4 zk = {0.0f, 0.0f, 0.0f, 0.0f};
    // cell state: lane owns (batch = quad*4 + half*2 + rl, j = p*16+col), rl = 0..1
    float cs[2] = {0.0f, 0.0f};

    float* const exw = &EX[half][p][lane][0];
    const float* const exr = &EX[half ^ 1][p][lane][0];

    __syncthreads();    // zero-init visible

    for (int it = 0; it < T_STEPS / 2; ++it) {
        #pragma unroll
        for (int u = 0; u < 2; ++u) {
            // this wave's single A-fragment (K-chunk half)
            const h8 A = *(const h8*)&H[u][col][half * 32 + quad * 8];

            if (half == 0) {
                // pack next-step Ax while lgkm pending; then issue x(t+3) prefetch
                Ax[u ^ 1].pk[0] = __builtin_amdgcn_cvt_pkrtz(xv[u][0], xv[u][1]);
                Ax[u ^ 1].pk[1] = __builtin_amdgcn_cvt_pkrtz(xv[u][2], xv[u][3]);
                Ax[u ^ 1].pk[2] = __builtin_amdgcn_cvt_pkrtz(x4[u], 0.0f);
                int tn = 2 * it + u + 3;
                tn = (tn < T_STEPS) ? tn : (T_STEPS - 1);
                const float* xp = xb + tn * IN_F;
                xv[u] = *(const f4*)xp;     // stays in flight (no vmcnt drain at barriers)
                x4[u] = xp[4];
            }

            // partial-K MFMAs
            f4 acc[4];
            if (half == 0) {
                #pragma unroll
                for (int q = 0; q < 4; ++q) {
                    f4 a = __builtin_amdgcn_mfma_f32_16x16x32_f16(Ax[u].v, Bx[q], zk, 0, 0, 0);
                    a = __builtin_amdgcn_mfma_f32_16x16x32_f16(A, Bf[q], a, 0, 0, 0);
                    acc[q] = a;
                }
            } else {
                #pragma unroll
                for (int q = 0; q < 4; ++q)
                    acc[q] = __builtin_amdgcn_mfma_f32_16x16x32_f16(A, Bf[q], zk, 0, 0, 0);
            }

            // split rows: keep mine (g0,g1), ship the other half's rows to partner.
            // all element indices compile-time inside the wave-uniform branch.
            float g0[4], g1[4];
            f4 pk0, pk1;
            if (half == 0) {
                pk0 = (f4){acc[0][2], acc[1][2], acc[2][2], acc[3][2]};
                pk1 = (f4){acc[0][3], acc[1][3], acc[2][3], acc[3][3]};
                #pragma unroll
                for (int q = 0; q < 4; ++q) { g0[q] = acc[q][0]; g1[q] = acc[q][1]; }
            } else {
                pk0 = (f4){acc[0][0], acc[1][0], acc[2][0], acc[3][0]};
                pk1 = (f4){acc[0][1], acc[1][1], acc[2][1], acc[3][1]};
                #pragma unroll
                for (int q = 0; q < 4; ++q) { g0[q] = acc[q][2]; g1[q] = acc[q][3]; }
            }
            *(f4*)exw       = pk0;
            *(f4*)(exw + 4) = pk1;

            asm volatile("s_waitcnt lgkmcnt(0)" ::: "memory");
            __builtin_amdgcn_s_barrier();
            asm volatile("" ::: "memory");

            // partner's partials for MY rows
            const f4 rd0 = *(const f4*)exr;
            const f4 rd1 = *(const f4*)(exr + 4);

            // elementwise LSTM for my 2 rows (batch = quad*4 + half*2 + rl)
            #pragma unroll
            for (int rl = 0; rl < 2; ++rl) {
                const f4 rd = rl ? rd1 : rd0;
                const float vi = (rl ? g1[0] : g0[0]) + rd[0];
                const float vf = (rl ? g1[1] : g0[1]) + rd[1];
                const float vg = (rl ? g1[2] : g0[2]) + rd[2];
                const float vo = (rl ? g1[3] : g0[3]) + rd[3];
                const float ig = frcp(1.0f + fexp2(fmaf(-K1, vi, nbi)));
                const float fg = frcp(1.0f + fexp2(fmaf(-K1, vf, nbf)));
                const float eg = fexp2(fmaf(K2, vg, pbg));
                const float gg = fmaf(-2.0f, frcp(eg + 1.0f), 1.0f);
                const float og = frcp(1.0f + fexp2(fmaf(-K1, vo, nbo)));
                cs[rl] = fmaf(fg, cs[rl], ig * gg);
                const float ec = fexp2(K2 * cs[rl]);
                const float th = fmaf(-2.0f, frcp(ec + 1.0f), 1.0f);
                H[u ^ 1][quad * 4 + half * 2 + rl][p * 16 + col] = (_Float16)(og * th);
            }

            // barrier WITHOUT vmcnt drain: H writes visible; EX safe to reuse next step
            asm volatile("s_waitcnt lgkmcnt(0)" ::: "memory");
            __builtin_amdgcn_s_barrier();
            asm volatile("" ::: "memory");
        }
    }

    // ---- output head: h_last lives in H[0]; batch b at row b ----
    if (tid < MB) {
        float a = bo[0];
        #pragma unroll 8
        for (int j = 0; j < D_H; ++j)
            a = fmaf((float)H[0][tid][j], Wo[j], a);
        out[bblk + tid] = a;
    }
}

extern "C" void kernel_launch(void* const* d_in, const int* in_sizes, int n_in,
                              void* d_out, int out_size, void* d_ws, size_t ws_size,
                              hipStream_t stream) {
    const float* x    = (const float*)d_in[0];
    const float* W0   = (const float*)d_in[1];
    const float* b0   = (const float*)d_in[2];
    const float* W_ih = (const float*)d_in[3];
    const float* W_hh = (const float*)d_in[4];
    const float* b_ih = (const float*)d_in[5];
    const float* b_hh = (const float*)d_in[6];
    const float* Wo   = (const float*)d_in[7];
    const float* bo   = (const float*)d_in[8];
    float* out = (float*)d_out;

    hipLaunchKernelGGL(lstm_mfma, dim3(B_TOT / MB), dim3(512), 0, stream,
                       x, W0, b0, W_ih, W_hh, b_ih, b_hh, Wo, bo, out);
}

// Round 7
// 416.716 us; speedup vs baseline: 1.0968x; 1.0968x over previous
//
#include <hip/hip_runtime.h>

#define B_TOT   4096
#define T_STEPS 512
#define IN_F    5
#define D_FC    32
#define D_H     64
#define MB      16      // batches per block; DENSE M-tile: batch b = A-row b
#define NROW    16
#define ROWE    72      // f16 elems per row (64 h + 8 pad; 144B rows, 16B-aligned)

typedef _Float16 h8 __attribute__((ext_vector_type(8)));
typedef __fp16   h2 __attribute__((ext_vector_type(2)));
typedef float    f4 __attribute__((ext_vector_type(4)));

__device__ __forceinline__ float fexp2(float x) { return __builtin_amdgcn_exp2f(x); }
__device__ __forceinline__ float frcp(float x)  { return __builtin_amdgcn_rcpf(x); }

__global__ __launch_bounds__(512) void lstm_mfma(
    const float* __restrict__ x,
    const float* __restrict__ W0,
    const float* __restrict__ b0,
    const float* __restrict__ W_ih,
    const float* __restrict__ W_hh,
    const float* __restrict__ b_ih,
    const float* __restrict__ b_hh,
    const float* __restrict__ Wo,
    const float* __restrict__ bo,
    float* __restrict__ out)
{
    // double-buffered h(t-1), f16: H[buf][batch-row][hidden]
    __shared__ __align__(16) _Float16 H[2][NROW][ROWE];

    const int tid  = threadIdx.x;
    const int lane = tid & 63;
    const int w    = tid >> 6;      // 0..7
    const int p    = w & 3;         // j-tile: owns hidden j in [p*16, p*16+16)
    const int eh   = w >> 2;        // elementwise half: acc regs {0,1} or {2,3}
    const int col  = lane & 15;
    const int quad = lane >> 4;
    const int bblk = blockIdx.x * MB;

    const float K1 = 1.4426950408889634f;   // log2(e)
    const float K2 = 2.8853900817779268f;   // 2*log2(e)

    // ---- resident W_hh B-fragments: FULL K (both halves duplicate MFMA work) ----
    h8 Bf[4][2];
    #pragma unroll
    for (int q = 0; q < 4; ++q) {
        const int row = q * 64 + p * 16 + col;
        #pragma unroll
        for (int c = 0; c < 2; ++c) {
            h8 f;
            #pragma unroll
            for (int jj = 0; jj < 8; ++jj) {
                const int k = c * 32 + quad * 8 + jj;
                f[jj] = (_Float16)W_hh[row * D_H + k];
            }
            Bf[q][c] = f;
        }
    }

    // ---- folded x-side weights: Weff = W_ih * W0 (256 x 5), K=32-padded frag ----
    h8 Bx[4];
    #pragma unroll
    for (int q = 0; q < 4; ++q) {
        #pragma unroll
        for (int jj = 0; jj < 8; ++jj) Bx[q][jj] = (_Float16)0.0f;
    }
    if (quad == 0) {
        #pragma unroll
        for (int q = 0; q < 4; ++q) {
            const int row = q * 64 + p * 16 + col;
            #pragma unroll
            for (int jj = 0; jj < IN_F; ++jj) {
                float s = 0.0f;
                #pragma unroll
                for (int m = 0; m < D_FC; ++m)
                    s = fmaf(W_ih[row * D_FC + m], W0[m * IN_F + jj], s);
                Bx[q][jj] = (_Float16)s;
            }
        }
    }

    // ---- folded bias, pre-scaled into the exp2 argument ----
    float sb[4];
    #pragma unroll
    for (int q = 0; q < 4; ++q) {
        const int row = q * 64 + p * 16 + col;
        float s = b_ih[row] + b_hh[row];
        #pragma unroll
        for (int m = 0; m < D_FC; ++m)
            s = fmaf(W_ih[row * D_FC + m], b0[m], s);
        sb[q] = s;
    }
    const float nbi = -K1 * sb[0];
    const float nbf = -K1 * sb[1];
    const float pbg =  K2 * sb[2];
    const float nbo = -K1 * sb[3];

    // ---- zero both LDS H buffers (h(-1)=0) ----
    for (int i = tid; i < 2 * NROW * ROWE; i += 512)
        ((_Float16*)H)[i] = (_Float16)0.0f;

    // ---- x feed: A-frag row = batch = col (halves duplicate; L1 absorbs) ----
    const float* xb = x + (size_t)(bblk + col) * T_STEPS * IN_F;

    union AxU { h8 v; h2 pk[4]; };
    AxU Ax[2];
    #pragma unroll
    for (int jj = 0; jj < 8; ++jj) { Ax[0].v[jj] = (_Float16)0.0f; Ax[1].v[jj] = (_Float16)0.0f; }
    {   // Ax[0] = x(0)
        const f4 v0 = *(const f4*)xb;
        const float s0 = xb[4];
        Ax[0].pk[0] = __builtin_amdgcn_cvt_pkrtz(v0[0], v0[1]);
        Ax[0].pk[1] = __builtin_amdgcn_cvt_pkrtz(v0[2], v0[3]);
        Ax[0].pk[2] = __builtin_amdgcn_cvt_pkrtz(s0, 0.0f);
    }
    // prefetch buffers: xv[0]=x(1), xv[1]=x(2)
    f4 xv[2]; float x4[2];
    xv[0] = *(const f4*)(xb + IN_F);      x4[0] = xb[IN_F + 4];
    xv[1] = *(const f4*)(xb + 2 * IN_F);  x4[1] = xb[2 * IN_F + 4];

    f4 zk = {0.0f, 0.0f, 0.0f, 0.0f};
    // cell state: lane owns (batch = quad*4 + eh*2 + rl, j = p*16+col), rl = 0..1
    float cs[2] = {0.0f, 0.0f};

    __syncthreads();    // zero-init visible

    for (int it = 0; it < T_STEPS / 2; ++it) {
        #pragma unroll
        for (int u = 0; u < 2; ++u) {
            // h(t-1) A-fragments from buffer u
            const h8 A1 = *(const h8*)&H[u][col][quad * 8];
            const h8 A2 = *(const h8*)&H[u][col][32 + quad * 8];

            // pack next-step Ax while lgkm pending; then issue x(t+3) prefetch
            Ax[u ^ 1].pk[0] = __builtin_amdgcn_cvt_pkrtz(xv[u][0], xv[u][1]);
            Ax[u ^ 1].pk[1] = __builtin_amdgcn_cvt_pkrtz(xv[u][2], xv[u][3]);
            Ax[u ^ 1].pk[2] = __builtin_amdgcn_cvt_pkrtz(x4[u], 0.0f);
            {
                int tn = 2 * it + u + 3;
                tn = (tn < T_STEPS) ? tn : (T_STEPS - 1);
                const float* xp = xb + tn * IN_F;
                xv[u] = *(const f4*)xp;     // stays in flight across barriers
                x4[u] = xp[4];
            }

            // 12 MFMAs (duplicated across halves): x-MFMA first (register operands)
            f4 acc[4];
            #pragma unroll
            for (int q = 0; q < 4; ++q) {
                f4 a = __builtin_amdgcn_mfma_f32_16x16x32_f16(Ax[u].v, Bx[q], zk, 0, 0, 0);
                a = __builtin_amdgcn_mfma_f32_16x16x32_f16(A1, Bf[q][0], a, 0, 0, 0);
                a = __builtin_amdgcn_mfma_f32_16x16x32_f16(A2, Bf[q][1], a, 0, 0, 0);
                acc[q] = a;
            }

            // my half's rows, extracted with compile-time indices (wave-uniform branch)
            float v0g[4], v1g[4];
            if (eh == 0) {
                #pragma unroll
                for (int q = 0; q < 4; ++q) { v0g[q] = acc[q][0]; v1g[q] = acc[q][1]; }
            } else {
                #pragma unroll
                for (int q = 0; q < 4; ++q) { v0g[q] = acc[q][2]; v1g[q] = acc[q][3]; }
            }

            // elementwise LSTM for my 2 rows (batch = quad*4 + eh*2 + rl)
            #pragma unroll
            for (int rl = 0; rl < 2; ++rl) {
                const float* vg = rl ? v1g : v0g;
                const float ig = frcp(1.0f + fexp2(fmaf(-K1, vg[0], nbi)));
                const float fg = frcp(1.0f + fexp2(fmaf(-K1, vg[1], nbf)));
                const float eg = fexp2(fmaf(K2, vg[2], pbg));
                const float gg = fmaf(-2.0f, frcp(eg + 1.0f), 1.0f);
                const float og = frcp(1.0f + fexp2(fmaf(-K1, vg[3], nbo)));
                cs[rl] = fmaf(fg, cs[rl], ig * gg);
                const float ec = fexp2(K2 * cs[rl]);
                const float th = fmaf(-2.0f, frcp(ec + 1.0f), 1.0f);
                H[u ^ 1][quad * 4 + eh * 2 + rl][p * 16 + col] = (_Float16)(og * th);
            }

            // single barrier WITHOUT vmcnt drain: H writes visible, x-prefetch in flight
            asm volatile("s_waitcnt lgkmcnt(0)" ::: "memory");
            __builtin_amdgcn_s_barrier();
            asm volatile("" ::: "memory");
        }
    }

    // ---- output head: h_last lives in H[0]; batch b at row b ----
    if (tid < MB) {
        float a = bo[0];
        #pragma unroll 8
        for (int j = 0; j < D_H; ++j)
            a = fmaf((float)H[0][tid][j], Wo[j], a);
        out[bblk + tid] = a;
    }
}

extern "C" void kernel_launch(void* const* d_in, const int* in_sizes, int n_in,
                              void* d_out, int out_size, void* d_ws, size_t ws_size,
                              hipStream_t stream) {
    const float* x    = (const float*)d_in[0];
    const float* W0   = (const float*)d_in[1];
    const float* b0   = (const float*)d_in[2];
    const float* W_ih = (const float*)d_in[3];
    const float* W_hh = (const float*)d_in[4];
    const float* b_ih = (const float*)d_in[5];
    const float* b_hh = (const float*)d_in[6];
    const float* Wo   = (const float*)d_in[7];
    const float* bo   = (const float*)d_in[8];
    float* out = (float*)d_out;

    hipLaunchKernelGGL(lstm_mfma, dim3(B_TOT / MB), dim3(512), 0, stream,
                       x, W0, b0, W_ih, W_hh, b_ih, b_hh, Wo, bo, out);
}